// Round 1
// baseline (896.667 us; speedup 1.0000x reference)
//
#include <hip/hip_runtime.h>

#define B_DIM 64
#define N_TOK 4096
#define C_DIM 512
#define C4 128                 // C_DIM / 4 (float4 per row)
#define NUM_KEEP 2458          // ceil(4096 * 0.6)
#define NON_KEEP 1638          // N_TOK - NUM_KEEP
#define SPLITS 16

// Decode the descending-order 32-bit key back to the original float score.
__device__ __forceinline__ float ts_decode_key(unsigned kd) {
    unsigned ka = ~kd;  // ascending-order key
    unsigned u = (ka & 0x80000000u) ? (ka ^ 0x80000000u) : ~ka;
    return __uint_as_float(u);
}

// One block per batch: build 64-bit keys (desc score | asc index), bitonic sort
// in LDS (stable-descending == jnp.argsort(-score)), emit order[], softmax
// weights over the non-kept tail, and the score_mask scatter.
__global__ __launch_bounds__(512) void ts_sort_kernel(
    const float* __restrict__ ax, const float* __restrict__ ay,
    int* __restrict__ order, float* __restrict__ weights,
    float* __restrict__ mask)
{
    __shared__ unsigned long long keys[N_TOK];   // 32 KB
    __shared__ float red[8];
    __shared__ float sh_vals[2];                 // [0]=max (tail head), [1]=1/sum
    const int b = blockIdx.x;
    const int tid = threadIdx.x;
    const int nthr = blockDim.x;

    const float* axb = ax + b * N_TOK;
    const float* ayb = ay + b * N_TOK;
    for (int i = tid; i < N_TOK; i += nthr) {
        float s = axb[i] + ayb[i];
        unsigned u = __float_as_uint(s);
        // descending-order key: larger score -> smaller key
        unsigned kd = (u & 0x80000000u) ? u : ~(u | 0x80000000u);
        keys[i] = ((unsigned long long)kd << 32) | (unsigned)i;
    }
    __syncthreads();

    // Bitonic sort, ascending on key64 => score desc, index asc on ties.
    for (int k = 2; k <= N_TOK; k <<= 1) {
        for (int j = k >> 1; j > 0; j >>= 1) {
            for (int i = tid; i < N_TOK; i += nthr) {
                int ixj = i ^ j;
                if (ixj > i) {
                    unsigned long long a = keys[i];
                    unsigned long long c = keys[ixj];
                    bool sw = ((i & k) == 0) ? (a > c) : (a < c);
                    if (sw) { keys[i] = c; keys[ixj] = a; }
                }
            }
            __syncthreads();
        }
    }

    // Softmax max over the tail = first element of the (sorted-desc) tail.
    if (tid == 0) sh_vals[0] = ts_decode_key((unsigned)(keys[NUM_KEEP] >> 32));
    __syncthreads();
    const float m = sh_vals[0];

    float local = 0.f;
    for (int p = tid; p < N_TOK; p += nthr) {
        unsigned long long kk = keys[p];
        int idx = (int)(kk & 0xFFFFFFFFu);
        order[b * N_TOK + p] = idx;
        mask[b * N_TOK + idx] = (p < NUM_KEEP) ? 1.0f : 0.0f;
        if (p >= NUM_KEEP) local += expf(ts_decode_key((unsigned)(kk >> 32)) - m);
    }
    // wave64 shuffle reduce, then cross-wave via LDS
    for (int off = 32; off > 0; off >>= 1) local += __shfl_down(local, off);
    if ((tid & 63) == 0) red[tid >> 6] = local;
    __syncthreads();
    if (tid == 0) {
        float s = 0.f;
        for (int w = 0; w < 512 / 64; ++w) s += red[w];
        sh_vals[1] = 1.0f / s;
    }
    __syncthreads();
    const float inv = sh_vals[1];
    for (int p = NUM_KEEP + tid; p < N_TOK; p += nthr) {
        float s = ts_decode_key((unsigned)(keys[p] >> 32));
        weights[b * NON_KEEP + (p - NUM_KEEP)] = expf(s - m) * inv;
    }
}

// select_tokens gather: 2 rows per 256-thread block, float4 lanes.
__global__ __launch_bounds__(256) void ts_gather_kernel(
    const float4* __restrict__ tokens, const int* __restrict__ order,
    float4* __restrict__ sel)
{
    int row = blockIdx.x * 2 + (threadIdx.x >> 7);   // [0, B*NUM_KEEP)
    int lane = threadIdx.x & 127;
    int b = row / NUM_KEEP;
    int k = row - b * NUM_KEEP;
    int idx = order[b * N_TOK + k];
    sel[(long long)row * C4 + lane] =
        tokens[((long long)(b * N_TOK) + idx) * C4 + lane];
}

// Weighted sum of non-kept rows, split SPLITS ways per batch -> partials.
__global__ __launch_bounds__(128) void ts_wsum_kernel(
    const float4* __restrict__ tokens, const int* __restrict__ order,
    const float* __restrict__ weights, float4* __restrict__ partials)
{
    int b = blockIdx.x / SPLITS;
    int split = blockIdx.x - b * SPLITS;
    int lane = threadIdx.x;  // 0..127
    const int per = (NON_KEEP + SPLITS - 1) / SPLITS;  // 103
    int j0 = split * per;
    int j1 = j0 + per; if (j1 > NON_KEEP) j1 = NON_KEEP;
    float4 acc = make_float4(0.f, 0.f, 0.f, 0.f);
    for (int j = j0; j < j1; ++j) {
        int idx = order[b * N_TOK + NUM_KEEP + j];
        float w = weights[b * NON_KEEP + j];
        float4 t = tokens[((long long)(b * N_TOK) + idx) * C4 + lane];
        acc.x += w * t.x; acc.y += w * t.y; acc.z += w * t.z; acc.w += w * t.w;
    }
    partials[(b * SPLITS + split) * C4 + lane] = acc;
}

__global__ __launch_bounds__(128) void ts_reduce_kernel(
    const float4* __restrict__ partials, float4* __restrict__ extra)
{
    int b = blockIdx.x;
    int lane = threadIdx.x;
    float4 acc = make_float4(0.f, 0.f, 0.f, 0.f);
    for (int s = 0; s < SPLITS; ++s) {
        float4 t = partials[(b * SPLITS + s) * C4 + lane];
        acc.x += t.x; acc.y += t.y; acc.z += t.z; acc.w += t.w;
    }
    extra[b * C4 + lane] = acc;
}

extern "C" void kernel_launch(void* const* d_in, const int* in_sizes, int n_in,
                              void* d_out, int out_size, void* d_ws, size_t ws_size,
                              hipStream_t stream) {
    const float* tokens = (const float*)d_in[0];   // (64, 4096, 512) f32
    const float* ax     = (const float*)d_in[1];   // (64, 4096) f32
    const float* ay     = (const float*)d_in[2];   // (64, 4096) f32

    float* out   = (float*)d_out;
    float* sel   = out;                                          // 64*2458*512
    float* extra = out + (long long)B_DIM * NUM_KEEP * C_DIM;    // 64*512
    float* mask  = extra + B_DIM * C_DIM;                        // 64*4096

    char* ws = (char*)d_ws;
    int*   order    = (int*)ws;                                            // 1 MB
    float* weights  = (float*)(ws + (size_t)B_DIM * N_TOK * 4);            // 419 KB
    float* partials = (float*)(ws + (size_t)B_DIM * N_TOK * 4
                                  + (size_t)B_DIM * NON_KEEP * 4);         // 2 MB (16-aligned)

    ts_sort_kernel<<<B_DIM, 512, 0, stream>>>(ax, ay, order, weights, mask);
    ts_gather_kernel<<<(B_DIM * NUM_KEEP) / 2, 256, 0, stream>>>(
        (const float4*)tokens, order, (float4*)sel);
    ts_wsum_kernel<<<B_DIM * SPLITS, 128, 0, stream>>>(
        (const float4*)tokens, order, weights, (float4*)partials);
    ts_reduce_kernel<<<B_DIM, 128, 0, stream>>>(
        (const float4*)partials, (float4*)extra);
}